// Round 1
// baseline (75.987 us; speedup 1.0000x reference)
//
#include <hip/hip_runtime.h>

#define NB 8
#define NL 512
#define ND 128

constexpr float CEXP = 2.8853900817779268f;   // 2*log2(e): exp2(CEXP*x) = e^{2x}

typedef float v2f __attribute__((ext_vector_type(2)));

// wpack: transpose+d4-pack weights (wp[(d>>2)*512 + e*4 + (d&3)] = w[e][d])
// so qk's weight loads are lane-coalesced.
__global__ __launch_bounds__(256) void wpack_kernel(
    const float* __restrict__ uw, const float* __restrict__ vw,
    float* __restrict__ uwp, float* __restrict__ vwp) {
  const int m = blockIdx.x >> 4;                        // 0: uw, 1: vw
  const int t = (blockIdx.x & 15) * 256 + threadIdx.x;  // 0..4095
  const float4* src = (const float4*)(m ? vw : uw);
  float4* dst = (float4*)(m ? vwp : uwp);
  const int e = t >> 5, d4 = t & 31;
  float4 v = src[e * 32 + d4];       // w[e][4d4..+3], coalesced read
  dst[d4 * 128 + e] = v;             // wp[d4][e][4]
}

// Kernel A: q = inp @ uw^T, k = inp @ vw^T.
//  eqp = exp2(CEXP*q), d4-packed-transposed [b][e4][l][4]  (VMEM stream)
//  ekq = exp2(CEXP*k), slot-interleaved [b][tile][e][8] with slot order
//        (i0,i4,i1,i5,i2,i6,i3,i7) so attn reads aligned SGPR pairs.
// inp rows are read via uniform s_loads (no LDS staging, no barrier).
__global__ __launch_bounds__(256) void qk_kernel(
    const float* __restrict__ inp, const float* __restrict__ uwp,
    const float* __restrict__ vwp, float* __restrict__ eqp,
    float* __restrict__ ekq) {
  __shared__ float qt[128][9];    // pad 9: conflict-free transpose
  const int b = blockIdx.x & 7;   // batch-per-XCD affinity (matches attn)
  const int l0 = (blockIdx.x >> 3) * 8;
  const int tid = threadIdx.x;

  const int e = tid & 127;
  const int half = tid >> 7;                 // 0 -> q (uw), 1 -> k (vw)
  const float* xrow = inp + (b * NL + l0) * ND;   // uniform base -> s_load
  const float4* W4 = (const float4*)(half ? vwp : uwp) + e;  // coalesced
  float acc[8];
#pragma unroll
  for (int r = 0; r < 8; ++r) acc[r] = 0.f;
  float4 w = W4[0];
  for (int d4 = 0; d4 < 32; ++d4) {
    float4 wn = W4[(size_t)((d4 + 1 > 31) ? 31 : d4 + 1) * 128];
#pragma unroll
    for (int r = 0; r < 8; ++r) {
      // uniform address -> scalar loads, broadcast as SGPR operands
      float4 x = *((const float4*)&xrow[r * ND + 4 * d4]);
      acc[r] = fmaf(w.x, x.x, acc[r]);
      acc[r] = fmaf(w.y, x.y, acc[r]);
      acc[r] = fmaf(w.z, x.z, acc[r]);
      acc[r] = fmaf(w.w, x.w, acc[r]);
    }
    w = wn;
  }
  if (half) {
    float* ekb = ekq + ((size_t)(b * 64 + (l0 >> 3)) * 128 + e) * 8;
#pragma unroll
    for (int r = 0; r < 8; ++r) {
      const int slot = (r & 3) * 2 + (r >> 2);
      ekb[slot] = __builtin_amdgcn_exp2f(CEXP * acc[r]);  // 32B/thread
    }
  } else {
#pragma unroll
    for (int r = 0; r < 8; ++r)
      qt[e][r] = __builtin_amdgcn_exp2f(CEXP * acc[r]);
  }
  __syncthreads();
  {
    // all 256 threads: thread -> (e4 = tid>>3, r = tid&7)
    const int e4 = tid >> 3, r = tid & 7;
    float4 v = make_float4(qt[4 * e4][r], qt[4 * e4 + 1][r],
                           qt[4 * e4 + 2][r], qt[4 * e4 + 3][r]);
    ((float4*)eqp)[(b * 32 + e4) * NL + l0 + r] = v;
  }
}

// Kernel B: 8-row i-tile, 1024 threads, 512 blocks.
// d-dimension split across two half-groups (dh = tid>>9): each half-group
// of 8 waves computes a partial acc over 64 of the 128 d's, combined via
// LDS. This doubles resident waves/SIMD (4 -> 8) to cover the rcp chain +
// s_load latency the 512-thread version exposed (VALUBusy was ~50%).
// Rows paired (i, i+4) into lo/hi halves of v2f (v_pk_*); quad-rcp per
// half. ek comes from GLOBAL via uniform loads -> SGPR pairs feeding
// v_pk_fma directly: NO ds_read in the score loop.
__global__ __launch_bounds__(1024, 8) void attn_kernel(
    const float* __restrict__ inp, const float* __restrict__ aw,
    const float* __restrict__ eqp, const float* __restrict__ ekq,
    float* __restrict__ out, float* __restrict__ attn) {
  __shared__ v2f red[8][8][64];        // PV partials (32KB); aliased accred
  __shared__ float attn_lds[8][512];   // 16KB
  __shared__ float rsum[8][8];

  const int b = blockIdx.x & 7;       // batch-per-XCD affinity
  const int i0 = (blockIdx.x >> 3) * 8;
  const int tid = threadIdx.x;
  const int lane = tid & 63;
  const int wid = tid >> 6;           // 0..15
  const int j = tid & 511;            // owned column
  const int dh = tid >> 9;            // d-half: 0 -> d<64, 1 -> d>=64 (wave-uniform)

  // ---- score stage: thread owns column j; 8 rows as 4 v2f pairs,
  // covering 16 of the 32 d4-steps (its d-half).
  v2f acc04 = {0.f, 0.f}, acc15 = {0.f, 0.f};
  v2f acc26 = {0.f, 0.f}, acc37 = {0.f, 0.f};
  const v2f ONE2 = {1.f, 1.f};
  const float4* eq4 =
      (const float4*)eqp + (size_t)(b * 32 + dh * 16) * NL + j;
  const float4* aw4 = (const float4*)aw + dh * 16;
  // uniform pointer: pairs (e_i0,e_i4),(e_i1,e_i5),(e_i2,e_i6),(e_i3,e_i7)
  const v2f* ekq2 =
      (const v2f*)(ekq + (size_t)(b * 64 + (i0 >> 3)) * 128 * 8) + dh * 256;
  float4 eA = eq4[0];
  float4 eB = eq4[NL];
#pragma unroll 4
  for (int d4 = 0; d4 < 16; ++d4) {
    const int nf = (d4 + 2 > 15) ? 15 : d4 + 2;      // 2-deep prefetch
    float4 eC = eq4[(size_t)nf * NL];
    float4 na4 = aw4[d4];                            // uniform -> s_load
#pragma unroll
    for (int dd = 0; dd < 4; ++dd) {
      const int d = 4 * d4 + dd;                     // local d within half
      const float eqs = (dd == 0) ? eA.x : (dd == 1) ? eA.y
                       : (dd == 2) ? eA.z : eA.w;
      const float na = (dd == 0) ? na4.x : (dd == 1) ? na4.y
                      : (dd == 2) ? na4.z : na4.w;
      v2f e01 = ekq2[d * 4 + 0];   // uniform -> SGPR pair
      v2f e23 = ekq2[d * 4 + 1];
      v2f e45 = ekq2[d * 4 + 2];
      v2f e67 = ekq2[d * 4 + 3];
      v2f eq2 = {eqs, eqs};
      // p = 1 + eq*ek; tanh = 1 - 2/p; "+1" terms softmax-invariant,
      // the -2 is folded into the exp2 constant below.
      v2f Pa = __builtin_elementwise_fma(eq2, e01, ONE2);  // rows (0,4)
      v2f Pb = __builtin_elementwise_fma(eq2, e23, ONE2);  // rows (1,5)
      v2f Pc = __builtin_elementwise_fma(eq2, e45, ONE2);  // rows (2,6)
      v2f Pd = __builtin_elementwise_fma(eq2, e67, ONE2);  // rows (3,7)
      v2f M1 = Pa * Pb;    // (p0p1, p4p5)
      v2f M2 = Pc * Pd;    // (p2p3, p6p7)
      v2f Q = M1 * M2;     // (p0123, p4567)
      v2f NR = {na * __builtin_amdgcn_rcpf(Q.x),
                na * __builtin_amdgcn_rcpf(Q.y)};
      v2f T = NR * M2;     // (na/p01, na/p45)
      v2f U = NR * M1;     // (na/p23, na/p67)
      acc04 = __builtin_elementwise_fma(T, Pb, acc04);   // na/p0, na/p4
      acc15 = __builtin_elementwise_fma(T, Pa, acc15);
      acc26 = __builtin_elementwise_fma(U, Pd, acc26);
      acc37 = __builtin_elementwise_fma(U, Pc, acc37);
    }
    eA = eB;
    eB = eC;
  }
  float acc[8] = {acc04.x, acc15.x, acc26.x, acc37.x,
                  acc04.y, acc15.y, acc26.y, acc37.y};

  // ---- combine the two d-half partials through LDS (alias red buffer)
  float* accred = (float*)red;
  if (dh) {
#pragma unroll
    for (int i = 0; i < 8; ++i) accred[i * 512 + j] = acc[i];
  }
  __syncthreads();

  // ---- softmax over j (dh==0 waves own it); score = -2*acc (fold -2
  // into exp2 constant); no max-subtraction: |exp2 arg| <= ~26, safe.
  float ex[8];
  if (!dh) {
#pragma unroll
    for (int i = 0; i < 8; ++i) {
      float a = acc[i] + accred[i * 512 + j];
      float e = __builtin_amdgcn_exp2f(a * (-CEXP));
      ex[i] = e;
      float s = e;
#pragma unroll
      for (int off = 32; off; off >>= 1) s += __shfl_xor(s, off);
      if (lane == 0) rsum[wid][i] = s;
    }
  }
  __syncthreads();
  if (!dh) {
    float* attnb = attn + (size_t)(b * NL + i0) * NL;
#pragma unroll
    for (int i = 0; i < 8; ++i) {
      float s = ((rsum[0][i] + rsum[1][i]) + (rsum[2][i] + rsum[3][i])) +
                ((rsum[4][i] + rsum[5][i]) + (rsum[6][i] + rsum[7][i]));
      float a = ex[i] * __builtin_amdgcn_rcpf(s);
      attn_lds[i][j] = a;
      attnb[i * NL + j] = a;           // coalesced
    }
  }
  __syncthreads();

  // ---- PV: 16 waves; wave w owns j in [64*(w&7), +64) for the 4 rows
  // of its row-group rg = w>>3; lane owns a v2f d-pair.
  const int jbase = (wid & 7) * 64;
  const int rg = wid >> 3;
  v2f po[4];
#pragma unroll
  for (int i = 0; i < 4; ++i) po[i] = (v2f){0.f, 0.f};
  const v2f* inp2 = (const v2f*)(inp + b * NL * ND);
  for (int jj4 = 0; jj4 < 16; ++jj4) {
    const int jc = jbase + jj4 * 4;
    v2f x0 = inp2[(jc + 0) * 64 + lane];   // coalesced (L2-resident)
    v2f x1 = inp2[(jc + 1) * 64 + lane];
    v2f x2 = inp2[(jc + 2) * 64 + lane];
    v2f x3 = inp2[(jc + 3) * 64 + lane];
#pragma unroll
    for (int i = 0; i < 4; ++i) {
      float4 a4 = *((const float4*)&attn_lds[rg * 4 + i][jc]);  // broadcast
      po[i] = __builtin_elementwise_fma((v2f){a4.x, a4.x}, x0, po[i]);
      po[i] = __builtin_elementwise_fma((v2f){a4.y, a4.y}, x1, po[i]);
      po[i] = __builtin_elementwise_fma((v2f){a4.z, a4.z}, x2, po[i]);
      po[i] = __builtin_elementwise_fma((v2f){a4.w, a4.w}, x3, po[i]);
    }
  }
  // waves (w, w+8) write disjoint i-slots of plane w&7: no conflicts
#pragma unroll
  for (int i = 0; i < 4; ++i) red[wid & 7][rg * 4 + i][lane] = po[i];
  __syncthreads();
  if (wid < 8) {
    const int i2 = wid, dl = lane;
    v2f s = red[0][i2][dl];
#pragma unroll
    for (int p = 1; p < 8; ++p) s += red[p][i2][dl];
    *(v2f*)&out[(size_t)(b * NL + i0 + i2) * ND + dl * 2] = s;
  }
}

extern "C" void kernel_launch(void* const* d_in, const int* in_sizes, int n_in,
                              void* d_out, int out_size, void* d_ws,
                              size_t ws_size, hipStream_t stream) {
  const float* inp = (const float*)d_in[0];
  const float* uw = (const float*)d_in[1];
  const float* vw = (const float*)d_in[2];
  const float* aw = (const float*)d_in[3];
  float* out = (float*)d_out;
  float* attn = out + NB * NL * ND;        // tuple order: (out, attn)
  float* eqp = (float*)d_ws;               // [B][32][512][4] packed exp2 q
  float* ekq = eqp + NB * ND * NL;         // [B][64][128][8] slot-interleaved
  size_t need = (size_t)2 * NB * ND * NL * 4 + 32768 * 4;
  float* wp = (ws_size >= need) ? (ekq + NB * ND * NL) : (attn);
  float* uwp = wp;                 // 16384
  float* vwp = wp + 16384;         // 16384
  wpack_kernel<<<dim3(32), 256, 0, stream>>>(uw, vw, uwp, vwp);
  qk_kernel<<<dim3(NB * 64), 256, 0, stream>>>(inp, uwp, vwp, eqp, ekq);
  attn_kernel<<<dim3(NB * 64), 1024, 0, stream>>>(inp, aw, eqp, ekq, out, attn);
}

// Round 2
// 58.370 us; speedup vs baseline: 1.3018x; 1.3018x over previous
//
#include <hip/hip_runtime.h>

#define NB 8
#define NL 512
#define ND 128

constexpr float CEXP = 2.8853900817779268f;   // 2*log2(e): exp2(CEXP*x) = e^{2x}

typedef float v2f __attribute__((ext_vector_type(2)));

// wpack: transpose+d4-pack weights (wp[(d>>2)*512 + e*4 + (d&3)] = w[e][d])
// so qk's weight loads are lane-coalesced.
__global__ __launch_bounds__(256) void wpack_kernel(
    const float* __restrict__ uw, const float* __restrict__ vw,
    float* __restrict__ uwp, float* __restrict__ vwp) {
  const int m = blockIdx.x >> 4;                        // 0: uw, 1: vw
  const int t = (blockIdx.x & 15) * 256 + threadIdx.x;  // 0..4095
  const float4* src = (const float4*)(m ? vw : uw);
  float4* dst = (float4*)(m ? vwp : uwp);
  const int e = t >> 5, d4 = t & 31;
  float4 v = src[e * 32 + d4];       // w[e][4d4..+3], coalesced read
  dst[d4 * 128 + e] = v;             // wp[d4][e][4]
}

// Kernel A: q = inp @ uw^T, k = inp @ vw^T.
//  eqp = exp2(CEXP*q), d4-packed-transposed [b][e4][l][4]  (VMEM stream)
//  ekq = exp2(CEXP*k), slot-interleaved [b][tile][e][8] with slot order
//        (i0,i4,i1,i5,i2,i6,i3,i7) so attn reads aligned SGPR pairs.
// inp rows are read via uniform s_loads (no LDS staging, no barrier).
__global__ __launch_bounds__(256) void qk_kernel(
    const float* __restrict__ inp, const float* __restrict__ uwp,
    const float* __restrict__ vwp, float* __restrict__ eqp,
    float* __restrict__ ekq) {
  __shared__ float qt[128][9];    // pad 9: conflict-free transpose
  const int b = blockIdx.x & 7;   // batch-per-XCD affinity (matches attn)
  const int l0 = (blockIdx.x >> 3) * 8;
  const int tid = threadIdx.x;

  const int e = tid & 127;
  const int half = tid >> 7;                 // 0 -> q (uw), 1 -> k (vw)
  const float* xrow = inp + (b * NL + l0) * ND;   // uniform base -> s_load
  const float4* W4 = (const float4*)(half ? vwp : uwp) + e;  // coalesced
  float acc[8];
#pragma unroll
  for (int r = 0; r < 8; ++r) acc[r] = 0.f;
  float4 w = W4[0];
  for (int d4 = 0; d4 < 32; ++d4) {
    float4 wn = W4[(size_t)((d4 + 1 > 31) ? 31 : d4 + 1) * 128];
#pragma unroll
    for (int r = 0; r < 8; ++r) {
      // uniform address -> scalar loads, broadcast as SGPR operands
      float4 x = *((const float4*)&xrow[r * ND + 4 * d4]);
      acc[r] = fmaf(w.x, x.x, acc[r]);
      acc[r] = fmaf(w.y, x.y, acc[r]);
      acc[r] = fmaf(w.z, x.z, acc[r]);
      acc[r] = fmaf(w.w, x.w, acc[r]);
    }
    w = wn;
  }
  if (half) {
    float* ekb = ekq + ((size_t)(b * 64 + (l0 >> 3)) * 128 + e) * 8;
#pragma unroll
    for (int r = 0; r < 8; ++r) {
      const int slot = (r & 3) * 2 + (r >> 2);
      ekb[slot] = __builtin_amdgcn_exp2f(CEXP * acc[r]);  // 32B/thread
    }
  } else {
#pragma unroll
    for (int r = 0; r < 8; ++r)
      qt[e][r] = __builtin_amdgcn_exp2f(CEXP * acc[r]);
  }
  __syncthreads();
  {
    // all 256 threads: thread -> (e4 = tid>>3, r = tid&7)
    const int e4 = tid >> 3, r = tid & 7;
    float4 v = make_float4(qt[4 * e4][r], qt[4 * e4 + 1][r],
                           qt[4 * e4 + 2][r], qt[4 * e4 + 3][r]);
    ((float4*)eqp)[(b * 32 + e4) * NL + l0 + r] = v;
  }
}

// Kernel B: 8-row i-tile, 1024 threads, 512 blocks.
// d-dimension split across two half-groups (dh = tid>>9): each half-group
// of 8 waves computes a partial acc over 64 of the 128 d's, combined via
// LDS. Doubles resident waves/SIMD (4 -> 8) vs the 512-thread version.
// CRITICAL: dh goes through readfirstlane so the compiler proves the
// ekq/aw pointers wave-uniform -> s_load into SGPRs feeding v_pk_fma
// (round-1 regression: divergent dh turned these into per-lane VMEM
// broadcasts, SGPR_Count 112->32, VALUBusy 53->33, 39us -> 68us).
__global__ __launch_bounds__(1024, 8) void attn_kernel(
    const float* __restrict__ inp, const float* __restrict__ aw,
    const float* __restrict__ eqp, const float* __restrict__ ekq,
    float* __restrict__ out, float* __restrict__ attn) {
  __shared__ v2f red[8][8][64];        // PV partials (32KB); aliased accred
  __shared__ float attn_lds[8][512];   // 16KB
  __shared__ float rsum[8][8];

  const int b = blockIdx.x & 7;       // batch-per-XCD affinity
  const int i0 = (blockIdx.x >> 3) * 8;
  const int tid = threadIdx.x;
  const int lane = tid & 63;
  const int wid = tid >> 6;           // 0..15
  const int j = tid & 511;            // owned column
  // d-half: wave-uniform (lanes differ only in bits 0..5); readfirstlane
  // makes it an SGPR so divergence analysis keeps dependent pointers scalar.
  const int dh = __builtin_amdgcn_readfirstlane(tid >> 9);

  // ---- score stage: thread owns column j; 8 rows as 4 v2f pairs,
  // covering 16 of the 32 d4-steps (its d-half).
  v2f acc04 = {0.f, 0.f}, acc15 = {0.f, 0.f};
  v2f acc26 = {0.f, 0.f}, acc37 = {0.f, 0.f};
  const v2f ONE2 = {1.f, 1.f};
  const float4* eq4 =
      (const float4*)eqp + (size_t)(b * 32 + dh * 16) * NL + j;
  const float4* aw4 = (const float4*)aw + dh * 16;   // uniform -> s_load
  // uniform pointer: pairs (e_i0,e_i4),(e_i1,e_i5),(e_i2,e_i6),(e_i3,e_i7)
  const v2f* ekq2 =
      (const v2f*)(ekq + (size_t)(b * 64 + (i0 >> 3)) * 128 * 8) + dh * 256;
  float4 eA = eq4[0];
  float4 eB = eq4[NL];
#pragma unroll 4
  for (int d4 = 0; d4 < 16; ++d4) {
    const int nf = (d4 + 2 > 15) ? 15 : d4 + 2;      // 2-deep prefetch
    float4 eC = eq4[(size_t)nf * NL];
    float4 na4 = aw4[d4];                            // uniform -> s_load
#pragma unroll
    for (int dd = 0; dd < 4; ++dd) {
      const int d = 4 * d4 + dd;                     // local d within half
      const float eqs = (dd == 0) ? eA.x : (dd == 1) ? eA.y
                       : (dd == 2) ? eA.z : eA.w;
      const float na = (dd == 0) ? na4.x : (dd == 1) ? na4.y
                      : (dd == 2) ? na4.z : na4.w;
      v2f e01 = ekq2[d * 4 + 0];   // uniform -> SGPR pair
      v2f e23 = ekq2[d * 4 + 1];
      v2f e45 = ekq2[d * 4 + 2];
      v2f e67 = ekq2[d * 4 + 3];
      v2f eq2 = {eqs, eqs};
      // p = 1 + eq*ek; tanh = 1 - 2/p; "+1" terms softmax-invariant,
      // the -2 is folded into the exp2 constant below.
      v2f Pa = __builtin_elementwise_fma(eq2, e01, ONE2);  // rows (0,4)
      v2f Pb = __builtin_elementwise_fma(eq2, e23, ONE2);  // rows (1,5)
      v2f Pc = __builtin_elementwise_fma(eq2, e45, ONE2);  // rows (2,6)
      v2f Pd = __builtin_elementwise_fma(eq2, e67, ONE2);  // rows (3,7)
      v2f M1 = Pa * Pb;    // (p0p1, p4p5)
      v2f M2 = Pc * Pd;    // (p2p3, p6p7)
      v2f Q = M1 * M2;     // (p0123, p4567)
      v2f NR = {na * __builtin_amdgcn_rcpf(Q.x),
                na * __builtin_amdgcn_rcpf(Q.y)};
      v2f T = NR * M2;     // (na/p01, na/p45)
      v2f U = NR * M1;     // (na/p23, na/p67)
      acc04 = __builtin_elementwise_fma(T, Pb, acc04);   // na/p0, na/p4
      acc15 = __builtin_elementwise_fma(T, Pa, acc15);
      acc26 = __builtin_elementwise_fma(U, Pd, acc26);
      acc37 = __builtin_elementwise_fma(U, Pc, acc37);
    }
    eA = eB;
    eB = eC;
  }
  float acc[8] = {acc04.x, acc15.x, acc26.x, acc37.x,
                  acc04.y, acc15.y, acc26.y, acc37.y};

  // ---- combine the two d-half partials through LDS (alias red buffer)
  float* accred = (float*)red;
  if (dh) {
#pragma unroll
    for (int i = 0; i < 8; ++i) accred[i * 512 + j] = acc[i];
  }
  __syncthreads();

  // ---- softmax over j (dh==0 waves own it); score = -2*acc (fold -2
  // into exp2 constant); no max-subtraction: |exp2 arg| <= ~26, safe.
  float ex[8];
  if (!dh) {
#pragma unroll
    for (int i = 0; i < 8; ++i) {
      float a = acc[i] + accred[i * 512 + j];
      float e = __builtin_amdgcn_exp2f(a * (-CEXP));
      ex[i] = e;
      float s = e;
#pragma unroll
      for (int off = 32; off; off >>= 1) s += __shfl_xor(s, off);
      if (lane == 0) rsum[wid][i] = s;
    }
  }
  __syncthreads();
  if (!dh) {
    float* attnb = attn + (size_t)(b * NL + i0) * NL;
#pragma unroll
    for (int i = 0; i < 8; ++i) {
      float s = ((rsum[0][i] + rsum[1][i]) + (rsum[2][i] + rsum[3][i])) +
                ((rsum[4][i] + rsum[5][i]) + (rsum[6][i] + rsum[7][i]));
      float a = ex[i] * __builtin_amdgcn_rcpf(s);
      attn_lds[i][j] = a;
      attnb[i * NL + j] = a;           // coalesced
    }
  }
  __syncthreads();

  // ---- PV: 16 waves; wave w owns j in [64*(w&7), +64) for the 4 rows
  // of its row-group rg = w>>3; lane owns a v2f d-pair.
  const int jbase = (wid & 7) * 64;
  const int rg = wid >> 3;
  v2f po[4];
#pragma unroll
  for (int i = 0; i < 4; ++i) po[i] = (v2f){0.f, 0.f};
  const v2f* inp2 = (const v2f*)(inp + b * NL * ND);
  for (int jj4 = 0; jj4 < 16; ++jj4) {
    const int jc = jbase + jj4 * 4;
    v2f x0 = inp2[(jc + 0) * 64 + lane];   // coalesced (L2-resident)
    v2f x1 = inp2[(jc + 1) * 64 + lane];
    v2f x2 = inp2[(jc + 2) * 64 + lane];
    v2f x3 = inp2[(jc + 3) * 64 + lane];
#pragma unroll
    for (int i = 0; i < 4; ++i) {
      float4 a4 = *((const float4*)&attn_lds[rg * 4 + i][jc]);  // broadcast
      po[i] = __builtin_elementwise_fma((v2f){a4.x, a4.x}, x0, po[i]);
      po[i] = __builtin_elementwise_fma((v2f){a4.y, a4.y}, x1, po[i]);
      po[i] = __builtin_elementwise_fma((v2f){a4.z, a4.z}, x2, po[i]);
      po[i] = __builtin_elementwise_fma((v2f){a4.w, a4.w}, x3, po[i]);
    }
  }
  // waves (w, w+8) write disjoint i-slots of plane w&7: no conflicts
#pragma unroll
  for (int i = 0; i < 4; ++i) red[wid & 7][rg * 4 + i][lane] = po[i];
  __syncthreads();
  if (wid < 8) {
    const int i2 = wid, dl = lane;
    v2f s = red[0][i2][dl];
#pragma unroll
    for (int p = 1; p < 8; ++p) s += red[p][i2][dl];
    *(v2f*)&out[(size_t)(b * NL + i0 + i2) * ND + dl * 2] = s;
  }
}

extern "C" void kernel_launch(void* const* d_in, const int* in_sizes, int n_in,
                              void* d_out, int out_size, void* d_ws,
                              size_t ws_size, hipStream_t stream) {
  const float* inp = (const float*)d_in[0];
  const float* uw = (const float*)d_in[1];
  const float* vw = (const float*)d_in[2];
  const float* aw = (const float*)d_in[3];
  float* out = (float*)d_out;
  float* attn = out + NB * NL * ND;        // tuple order: (out, attn)
  float* eqp = (float*)d_ws;               // [B][32][512][4] packed exp2 q
  float* ekq = eqp + NB * ND * NL;         // [B][64][128][8] slot-interleaved
  size_t need = (size_t)2 * NB * ND * NL * 4 + 32768 * 4;
  float* wp = (ws_size >= need) ? (ekq + NB * ND * NL) : (attn);
  float* uwp = wp;                 // 16384
  float* vwp = wp + 16384;         // 16384
  wpack_kernel<<<dim3(32), 256, 0, stream>>>(uw, vw, uwp, vwp);
  qk_kernel<<<dim3(NB * 64), 256, 0, stream>>>(inp, uwp, vwp, eqp, ekq);
  attn_kernel<<<dim3(NB * 64), 1024, 0, stream>>>(inp, aw, eqp, ekq, out, attn);
}

// Round 3
// 57.623 us; speedup vs baseline: 1.3187x; 1.0130x over previous
//
#include <hip/hip_runtime.h>

#define NB 8
#define NL 512
#define ND 128

constexpr float CEXP = 2.8853900817779268f;   // 2*log2(e): exp2(CEXP*x) = e^{2x}

typedef float v2f __attribute__((ext_vector_type(2)));

// wpack: transpose+d4-pack weights (wp[(d>>2)*512 + e*4 + (d&3)] = w[e][d])
// so qk's weight loads are lane-coalesced.
__global__ __launch_bounds__(256) void wpack_kernel(
    const float* __restrict__ uw, const float* __restrict__ vw,
    float* __restrict__ uwp, float* __restrict__ vwp) {
  const int m = blockIdx.x >> 4;                        // 0: uw, 1: vw
  const int t = (blockIdx.x & 15) * 256 + threadIdx.x;  // 0..4095
  const float4* src = (const float4*)(m ? vw : uw);
  float4* dst = (float4*)(m ? vwp : uwp);
  const int e = t >> 5, d4 = t & 31;
  float4 v = src[e * 32 + d4];       // w[e][4d4..+3], coalesced read
  dst[d4 * 128 + e] = v;             // wp[d4][e][4]
}

// Kernel A: q = inp @ uw^T, k = inp @ vw^T.
//  eqp = exp2(CEXP*q), d4-packed-transposed [b][e4][l][4]  (VMEM stream)
//  ekq = exp2(CEXP*k), 4-row-tile interleaved [b][tile][e][4] with slot
//        order (i0,i2,i1,i3) so attn reads two aligned v2f SGPR pairs per d.
// inp rows are read via uniform s_loads (no LDS staging, no barrier).
__global__ __launch_bounds__(256) void qk_kernel(
    const float* __restrict__ inp, const float* __restrict__ uwp,
    const float* __restrict__ vwp, float* __restrict__ eqp,
    float* __restrict__ ekq) {
  __shared__ float qt[128][9];    // pad 9: conflict-free transpose
  const int b = blockIdx.x & 7;   // batch-per-XCD affinity (matches attn)
  const int l0 = (blockIdx.x >> 3) * 8;
  const int tid = threadIdx.x;

  const int e = tid & 127;
  const int half = tid >> 7;                 // 0 -> q (uw), 1 -> k (vw)
  const float* xrow = inp + (b * NL + l0) * ND;   // uniform base -> s_load
  const float4* W4 = (const float4*)(half ? vwp : uwp) + e;  // coalesced
  float acc[8];
#pragma unroll
  for (int r = 0; r < 8; ++r) acc[r] = 0.f;
  float4 w = W4[0];
  for (int d4 = 0; d4 < 32; ++d4) {
    float4 wn = W4[(size_t)((d4 + 1 > 31) ? 31 : d4 + 1) * 128];
#pragma unroll
    for (int r = 0; r < 8; ++r) {
      // uniform address -> scalar loads, broadcast as SGPR operands
      float4 x = *((const float4*)&xrow[r * ND + 4 * d4]);
      acc[r] = fmaf(w.x, x.x, acc[r]);
      acc[r] = fmaf(w.y, x.y, acc[r]);
      acc[r] = fmaf(w.z, x.z, acc[r]);
      acc[r] = fmaf(w.w, x.w, acc[r]);
    }
    w = wn;
  }
  if (half) {
    float ek[8];
#pragma unroll
    for (int r = 0; r < 8; ++r)
      ek[r] = __builtin_amdgcn_exp2f(CEXP * acc[r]);
    // two 4-row tiles: slots (i0,i2,i1,i3) within each tile
    float4 lo = make_float4(ek[0], ek[2], ek[1], ek[3]);
    float4 hi = make_float4(ek[4], ek[6], ek[5], ek[7]);
    float4* ekb = (float4*)ekq + (size_t)(b * 128 + (l0 >> 2)) * 128 + e;
    ekb[0] = lo;       // tile l0/4,   coalesced across e
    ekb[128] = hi;     // tile l0/4+1, coalesced across e
  } else {
#pragma unroll
    for (int r = 0; r < 8; ++r)
      qt[e][r] = __builtin_amdgcn_exp2f(CEXP * acc[r]);
  }
  __syncthreads();
  {
    // all 256 threads: thread -> (e4 = tid>>3, r = tid&7)
    const int e4 = tid >> 3, r = tid & 7;
    float4 v = make_float4(qt[4 * e4][r], qt[4 * e4 + 1][r],
                           qt[4 * e4 + 2][r], qt[4 * e4 + 3][r]);
    ((float4*)eqp)[(b * 32 + e4) * NL + l0 + r] = v;
  }
}

// Kernel B: 4-row i-tile, 512 threads, 1024 blocks (4 blocks/CU -> 8
// waves/SIMD, 2x the 8-row version's residency). At pk_f32 = 4cy the
// 8-row quad-rcp machinery costs the same per row as plain dual-rcp
// (9 vs 10 cy/row/d), so halving the tile costs ~nothing arithmetically
// and doubles latency cover. ALL uniform values derive from blockIdx
// (round-1/2 lesson: threadIdx-derived "uniform" pointers break SMEM
// scalarization -> per-lane VMEM broadcasts, 39us -> 68us).
// Rows paired (0,2)/(1,3) into lo/hi halves of v2f (v_pk_*); dual-rcp.
// ek comes from GLOBAL via uniform loads -> SGPR pairs feeding v_pk_fma
// directly: NO ds_read in the score loop.
__global__ __launch_bounds__(512, 8) void attn_kernel(
    const float* __restrict__ inp, const float* __restrict__ aw,
    const float* __restrict__ eqp, const float* __restrict__ ekq,
    float* __restrict__ out, float* __restrict__ attn) {
  __shared__ v2f red[8][4][64];        // PV partials (16KB)
  __shared__ float attn_lds[4][512];   // 8KB
  __shared__ float rsum[8][4];

  const int b = blockIdx.x & 7;       // batch-per-XCD affinity
  const int i0 = (blockIdx.x >> 3) * 4;
  const int tid = threadIdx.x;
  const int lane = tid & 63;
  const int wid = tid >> 6;

  // ---- score stage: thread owns column j = tid; 4 rows as 2 v2f pairs
  v2f acc02 = {0.f, 0.f}, acc13 = {0.f, 0.f};
  const v2f ONE2 = {1.f, 1.f};
  const float4* eq4 = (const float4*)eqp + (size_t)(b * 32) * NL + tid;
  const float4* aw4 = (const float4*)aw;
  // uniform pointer: per d, pairs (e_i0,e_i2),(e_i1,e_i3)
  const v2f* ekq2 =
      (const v2f*)(ekq + (size_t)(b * 128 + (i0 >> 2)) * 128 * 4);
  float4 eA = eq4[0];
  float4 eB = eq4[NL];
#pragma unroll 4
  for (int d4 = 0; d4 < 32; ++d4) {
    const int nf = (d4 + 2 > 31) ? 31 : d4 + 2;      // 2-deep prefetch
    float4 eC = eq4[(size_t)nf * NL];
    float4 na4 = aw4[d4];                            // uniform -> s_load
#pragma unroll
    for (int dd = 0; dd < 4; ++dd) {
      const int d = 4 * d4 + dd;
      const float eqs = (dd == 0) ? eA.x : (dd == 1) ? eA.y
                       : (dd == 2) ? eA.z : eA.w;
      const float na = (dd == 0) ? na4.x : (dd == 1) ? na4.y
                      : (dd == 2) ? na4.z : na4.w;
      v2f e02 = ekq2[d * 2 + 0];   // uniform -> SGPR pair
      v2f e13 = ekq2[d * 2 + 1];
      v2f eq2 = {eqs, eqs};
      // p = 1 + eq*ek; tanh = 1 - 2/p; "+1" terms softmax-invariant,
      // the -2 is folded into the exp2 constant below.
      v2f Pa = __builtin_elementwise_fma(eq2, e02, ONE2);  // rows (0,2)
      v2f Pb = __builtin_elementwise_fma(eq2, e13, ONE2);  // rows (1,3)
      v2f M = Pa * Pb;    // (p0p1, p2p3)
      v2f NR = {na * __builtin_amdgcn_rcpf(M.x),
                na * __builtin_amdgcn_rcpf(M.y)};
      acc02 = __builtin_elementwise_fma(NR, Pb, acc02);   // na/p0, na/p2
      acc13 = __builtin_elementwise_fma(NR, Pa, acc13);   // na/p1, na/p3
    }
    eA = eB;
    eB = eC;
  }
  float acc[4] = {acc02.x, acc13.x, acc02.y, acc13.y};

  // ---- softmax over j; score = -2*acc (fold -2 into exp2 constant);
  // no max-subtraction: |exp2 arg| <= ~26, safe in f32.
  float sinv[4], ex[4];
#pragma unroll
  for (int i = 0; i < 4; ++i) {
    float e = __builtin_amdgcn_exp2f(acc[i] * (-CEXP));
    ex[i] = e;
    float s = e;
#pragma unroll
    for (int off = 32; off; off >>= 1) s += __shfl_xor(s, off);
    if (lane == 0) rsum[wid][i] = s;
  }
  __syncthreads();
#pragma unroll
  for (int i = 0; i < 4; ++i) {
    float s = ((rsum[0][i] + rsum[1][i]) + (rsum[2][i] + rsum[3][i])) +
              ((rsum[4][i] + rsum[5][i]) + (rsum[6][i] + rsum[7][i]));
    sinv[i] = __builtin_amdgcn_rcpf(s);
  }

  float* attnb = attn + (size_t)(b * NL + i0) * NL;
#pragma unroll
  for (int i = 0; i < 4; ++i) {
    float a = ex[i] * sinv[i];
    attn_lds[i][tid] = a;
    attnb[i * NL + tid] = a;           // coalesced
  }
  __syncthreads();

  // ---- PV: wave w owns j in [64w, 64w+64); lane owns v2f d-pair
  v2f po[4];
#pragma unroll
  for (int i = 0; i < 4; ++i) po[i] = (v2f){0.f, 0.f};
  const v2f* inp2 = (const v2f*)(inp + b * NL * ND);
  for (int jj4 = 0; jj4 < 16; ++jj4) {
    const int jc = wid * 64 + jj4 * 4;
    v2f x0 = inp2[(jc + 0) * 64 + lane];   // coalesced (L2-resident)
    v2f x1 = inp2[(jc + 1) * 64 + lane];
    v2f x2 = inp2[(jc + 2) * 64 + lane];
    v2f x3 = inp2[(jc + 3) * 64 + lane];
#pragma unroll
    for (int i = 0; i < 4; ++i) {
      float4 a4 = *((const float4*)&attn_lds[i][jc]);   // uniform broadcast
      po[i] = __builtin_elementwise_fma((v2f){a4.x, a4.x}, x0, po[i]);
      po[i] = __builtin_elementwise_fma((v2f){a4.y, a4.y}, x1, po[i]);
      po[i] = __builtin_elementwise_fma((v2f){a4.z, a4.z}, x2, po[i]);
      po[i] = __builtin_elementwise_fma((v2f){a4.w, a4.w}, x3, po[i]);
    }
  }
#pragma unroll
  for (int i = 0; i < 4; ++i) red[wid][i][lane] = po[i];
  __syncthreads();
  if (wid < 4) {
    const int i2 = wid, dl = lane;
    v2f s = red[0][i2][dl];
#pragma unroll
    for (int p = 1; p < 8; ++p) s += red[p][i2][dl];
    *(v2f*)&out[(size_t)(b * NL + i0 + i2) * ND + dl * 2] = s;
  }
}

extern "C" void kernel_launch(void* const* d_in, const int* in_sizes, int n_in,
                              void* d_out, int out_size, void* d_ws,
                              size_t ws_size, hipStream_t stream) {
  const float* inp = (const float*)d_in[0];
  const float* uw = (const float*)d_in[1];
  const float* vw = (const float*)d_in[2];
  const float* aw = (const float*)d_in[3];
  float* out = (float*)d_out;
  float* attn = out + NB * NL * ND;        // tuple order: (out, attn)
  float* eqp = (float*)d_ws;               // [B][32][512][4] packed exp2 q
  float* ekq = eqp + NB * ND * NL;         // [B][128][128][4] tile-interleaved
  size_t need = (size_t)2 * NB * ND * NL * 4 + 32768 * 4;
  float* wp = (ws_size >= need) ? (ekq + NB * ND * NL) : (attn);
  float* uwp = wp;                 // 16384
  float* vwp = wp + 16384;         // 16384
  wpack_kernel<<<dim3(32), 256, 0, stream>>>(uw, vw, uwp, vwp);
  qk_kernel<<<dim3(NB * 64), 256, 0, stream>>>(inp, uwp, vwp, eqp, ekq);
  attn_kernel<<<dim3(NB * 128), 512, 0, stream>>>(inp, aw, eqp, ekq, out, attn);
}

// Round 4
// 57.321 us; speedup vs baseline: 1.3257x; 1.0053x over previous
//
#include <hip/hip_runtime.h>

#define NB 8
#define NL 512
#define ND 128

constexpr float CEXP = 2.8853900817779268f;   // 2*log2(e): exp2(CEXP*x) = e^{2x}

typedef float v2f __attribute__((ext_vector_type(2)));

// wpack: transpose+d4-pack weights (wp[(d>>2)*512 + e*4 + (d&3)] = w[e][d])
// so qk's weight loads are lane-coalesced.
__global__ __launch_bounds__(256) void wpack_kernel(
    const float* __restrict__ uw, const float* __restrict__ vw,
    float* __restrict__ uwp, float* __restrict__ vwp) {
  const int m = blockIdx.x >> 4;                        // 0: uw, 1: vw
  const int t = (blockIdx.x & 15) * 256 + threadIdx.x;  // 0..4095
  const float4* src = (const float4*)(m ? vw : uw);
  float4* dst = (float4*)(m ? vwp : uwp);
  const int e = t >> 5, d4 = t & 31;
  float4 v = src[e * 32 + d4];       // w[e][4d4..+3], coalesced read
  dst[d4 * 128 + e] = v;             // wp[d4][e][4]
}

// Kernel A: q = inp @ uw^T, k = inp @ vw^T.
//  eqp = exp2(CEXP*q), d4-packed-transposed [b][e4][l][4]  (VMEM stream)
//  ekq = exp2(CEXP*k), 16-row-tile interleaved [b][tile16][e][16]:
//        slots (i0,i4,i1,i5,i2,i6,i3,i7 | i8,i12,i9,i13,i10,i14,i11,i15)
//        so attn reads aligned v2f SGPR pairs for two quad-rcp groups.
// inp rows are read via uniform s_loads (no LDS staging, no barrier).
__global__ __launch_bounds__(256) void qk_kernel(
    const float* __restrict__ inp, const float* __restrict__ uwp,
    const float* __restrict__ vwp, float* __restrict__ eqp,
    float* __restrict__ ekq) {
  __shared__ float qt[128][9];    // pad 9: conflict-free transpose
  const int b = blockIdx.x & 7;   // batch-per-XCD affinity (matches attn)
  const int l0 = (blockIdx.x >> 3) * 8;
  const int tid = threadIdx.x;

  const int e = tid & 127;
  const int half = tid >> 7;                 // 0 -> q (uw), 1 -> k (vw)
  const float* xrow = inp + (b * NL + l0) * ND;   // uniform base -> s_load
  const float4* W4 = (const float4*)(half ? vwp : uwp) + e;  // coalesced
  float acc[8];
#pragma unroll
  for (int r = 0; r < 8; ++r) acc[r] = 0.f;
  float4 w = W4[0];
  for (int d4 = 0; d4 < 32; ++d4) {
    float4 wn = W4[(size_t)((d4 + 1 > 31) ? 31 : d4 + 1) * 128];
#pragma unroll
    for (int r = 0; r < 8; ++r) {
      // uniform address -> scalar loads, broadcast as SGPR operands
      float4 x = *((const float4*)&xrow[r * ND + 4 * d4]);
      acc[r] = fmaf(w.x, x.x, acc[r]);
      acc[r] = fmaf(w.y, x.y, acc[r]);
      acc[r] = fmaf(w.z, x.z, acc[r]);
      acc[r] = fmaf(w.w, x.w, acc[r]);
    }
    w = wn;
  }
  if (half) {
    float ek[8];
#pragma unroll
    for (int r = 0; r < 8; ++r)
      ek[r] = __builtin_amdgcn_exp2f(CEXP * acc[r]);
    // 8-row group within a 16-row tile: slot = (r&3)*2 + (r>>2)
    float4 lo = make_float4(ek[0], ek[4], ek[1], ek[5]);
    float4 hi = make_float4(ek[2], ek[6], ek[3], ek[7]);
    float* ekb = ekq + ((size_t)(b * 32 + (l0 >> 4)) * 128 + e) * 16 +
                 ((l0 >> 3) & 1) * 8;
    *(float4*)&ekb[0] = lo;
    *(float4*)&ekb[4] = hi;
  } else {
#pragma unroll
    for (int r = 0; r < 8; ++r)
      qt[e][r] = __builtin_amdgcn_exp2f(CEXP * acc[r]);
  }
  __syncthreads();
  {
    // all 256 threads: thread -> (e4 = tid>>3, r = tid&7)
    const int e4 = tid >> 3, r = tid & 7;
    float4 v = make_float4(qt[4 * e4][r], qt[4 * e4 + 1][r],
                           qt[4 * e4 + 2][r], qt[4 * e4 + 3][r]);
    ((float4*)eqp)[(b * 32 + e4) * NL + l0 + r] = v;
  }
}

// Kernel B: 16-row i-tile, 512 threads, 256 blocks.
// Rounds 0/3 showed VALUBusy pinned ~52% at BOTH 27% and 50% occupancy:
// the packed-f32 pipe is saturated (pk ops occupy 4cy but count ~1 issue
// cy), so duration tracks issued work, not residency. 16 rows amortize
// the fixed per-d4 overhead (eq prefetch, addr math, loop ctrl) over 2x
// the rows of round-0 and halve per-batch L2 re-reads of eq/inp slabs.
// ALL uniform addresses derive from blockIdx (rounds 1/2 lesson:
// threadIdx-derived uniform pointers break SMEM scalarization).
// Two quad-rcp groups of 8 rows; rows paired (i,i+4) in v2f halves.
__global__ __launch_bounds__(512, 4) void attn_kernel(
    const float* __restrict__ inp, const float* __restrict__ aw,
    const float* __restrict__ eqp, const float* __restrict__ ekq,
    float* __restrict__ out, float* __restrict__ attn) {
  __shared__ v2f red[8][8][64];        // PV partials (32KB), 2 rounds
  __shared__ float attn_lds[16][512];  // 32KB
  __shared__ float rsum[8][16];

  const int b = blockIdx.x & 7;       // batch-per-XCD affinity
  const int i0 = (blockIdx.x >> 3) * 16;
  const int tid = threadIdx.x;
  const int lane = tid & 63;
  const int wid = tid >> 6;

  // ---- score stage: thread owns column j = tid; 16 rows as 8 v2f pairs
  v2f acc04 = {0.f, 0.f}, acc15 = {0.f, 0.f};
  v2f acc26 = {0.f, 0.f}, acc37 = {0.f, 0.f};
  v2f acc8C = {0.f, 0.f}, acc9D = {0.f, 0.f};
  v2f accAE = {0.f, 0.f}, accBF = {0.f, 0.f};
  const v2f ONE2 = {1.f, 1.f};
  const float4* eq4 = (const float4*)eqp + (size_t)(b * 32) * NL + tid;
  const float4* aw4 = (const float4*)aw;
  // uniform pointer: per d, 8 v2f pairs (2 groups x 4)
  const v2f* ekq2 =
      (const v2f*)(ekq + (size_t)(b * 32 + (i0 >> 4)) * 128 * 16);
  float4 eA = eq4[0];
  float4 eB = eq4[NL];
#pragma unroll 4
  for (int d4 = 0; d4 < 32; ++d4) {
    const int nf = (d4 + 2 > 31) ? 31 : d4 + 2;      // 2-deep prefetch
    float4 eC = eq4[(size_t)nf * NL];
    float4 na4 = aw4[d4];                            // uniform -> s_load
#pragma unroll
    for (int dd = 0; dd < 4; ++dd) {
      const int d = 4 * d4 + dd;
      const float eqs = (dd == 0) ? eA.x : (dd == 1) ? eA.y
                       : (dd == 2) ? eA.z : eA.w;
      const float na = (dd == 0) ? na4.x : (dd == 1) ? na4.y
                      : (dd == 2) ? na4.z : na4.w;
      v2f eq2 = {eqs, eqs};
      v2f NA2 = {na, na};
      // p = 1 + eq*ek; tanh = 1 - 2/p; "+1" terms softmax-invariant,
      // the -2 is folded into the exp2 constant below.
      // ---- group A: rows 0..7
      {
        v2f e01 = ekq2[d * 8 + 0];   // uniform -> SGPR pair
        v2f e23 = ekq2[d * 8 + 1];
        v2f e45 = ekq2[d * 8 + 2];
        v2f e67 = ekq2[d * 8 + 3];
        v2f Pa = __builtin_elementwise_fma(eq2, e01, ONE2);  // (0,4)
        v2f Pb = __builtin_elementwise_fma(eq2, e23, ONE2);  // (1,5)
        v2f Pc = __builtin_elementwise_fma(eq2, e45, ONE2);  // (2,6)
        v2f Pd = __builtin_elementwise_fma(eq2, e67, ONE2);  // (3,7)
        v2f M1 = Pa * Pb;    // (p0p1, p4p5)
        v2f M2 = Pc * Pd;    // (p2p3, p6p7)
        v2f Q = M1 * M2;     // (p0123, p4567)
        v2f R = {__builtin_amdgcn_rcpf(Q.x), __builtin_amdgcn_rcpf(Q.y)};
        v2f NR = NA2 * R;    // single pk_mul
        v2f T = NR * M2;     // (na/p01, na/p45)
        v2f U = NR * M1;     // (na/p23, na/p67)
        acc04 = __builtin_elementwise_fma(T, Pb, acc04);
        acc15 = __builtin_elementwise_fma(T, Pa, acc15);
        acc26 = __builtin_elementwise_fma(U, Pd, acc26);
        acc37 = __builtin_elementwise_fma(U, Pc, acc37);
      }
      // ---- group B: rows 8..15
      {
        v2f e01 = ekq2[d * 8 + 4];
        v2f e23 = ekq2[d * 8 + 5];
        v2f e45 = ekq2[d * 8 + 6];
        v2f e67 = ekq2[d * 8 + 7];
        v2f Pa = __builtin_elementwise_fma(eq2, e01, ONE2);  // (8,12)
        v2f Pb = __builtin_elementwise_fma(eq2, e23, ONE2);  // (9,13)
        v2f Pc = __builtin_elementwise_fma(eq2, e45, ONE2);  // (10,14)
        v2f Pd = __builtin_elementwise_fma(eq2, e67, ONE2);  // (11,15)
        v2f M1 = Pa * Pb;
        v2f M2 = Pc * Pd;
        v2f Q = M1 * M2;
        v2f R = {__builtin_amdgcn_rcpf(Q.x), __builtin_amdgcn_rcpf(Q.y)};
        v2f NR = NA2 * R;
        v2f T = NR * M2;
        v2f U = NR * M1;
        acc8C = __builtin_elementwise_fma(T, Pb, acc8C);
        acc9D = __builtin_elementwise_fma(T, Pa, acc9D);
        accAE = __builtin_elementwise_fma(U, Pd, accAE);
        accBF = __builtin_elementwise_fma(U, Pc, accBF);
      }
    }
    eA = eB;
    eB = eC;
  }
  float acc[16] = {acc04.x, acc15.x, acc26.x, acc37.x,
                   acc04.y, acc15.y, acc26.y, acc37.y,
                   acc8C.x, acc9D.x, accAE.x, accBF.x,
                   acc8C.y, acc9D.y, accAE.y, accBF.y};

  // ---- softmax over j; score = -2*acc (fold -2 into exp2 constant);
  // no max-subtraction: |exp2 arg| <= ~26, safe in f32.
  float ex[16];
#pragma unroll
  for (int i = 0; i < 16; ++i) {
    float e = __builtin_amdgcn_exp2f(acc[i] * (-CEXP));
    ex[i] = e;
    float s = e;
#pragma unroll
    for (int off = 32; off; off >>= 1) s += __shfl_xor(s, off);
    if (lane == 0) rsum[wid][i] = s;
  }
  __syncthreads();
  float* attnb = attn + (size_t)(b * NL + i0) * NL;
#pragma unroll
  for (int i = 0; i < 16; ++i) {
    float s = ((rsum[0][i] + rsum[1][i]) + (rsum[2][i] + rsum[3][i])) +
              ((rsum[4][i] + rsum[5][i]) + (rsum[6][i] + rsum[7][i]));
    float a = ex[i] * __builtin_amdgcn_rcpf(s);
    attn_lds[i][tid] = a;
    attnb[i * NL + tid] = a;           // coalesced
  }
  __syncthreads();

  // ---- PV: wave w owns j in [64w, 64w+64); lane owns v2f d-pair.
  // All 16 rows accumulated in registers; x-loads done once.
  v2f po[16];
#pragma unroll
  for (int i = 0; i < 16; ++i) po[i] = (v2f){0.f, 0.f};
  const v2f* inp2 = (const v2f*)(inp + b * NL * ND);
  for (int jj4 = 0; jj4 < 16; ++jj4) {
    const int jc = wid * 64 + jj4 * 4;
    v2f x0 = inp2[(jc + 0) * 64 + lane];   // coalesced (L2-resident)
    v2f x1 = inp2[(jc + 1) * 64 + lane];
    v2f x2 = inp2[(jc + 2) * 64 + lane];
    v2f x3 = inp2[(jc + 3) * 64 + lane];
#pragma unroll
    for (int i = 0; i < 16; ++i) {
      float4 a4 = *((const float4*)&attn_lds[i][jc]);   // uniform broadcast
      po[i] = __builtin_elementwise_fma((v2f){a4.x, a4.x}, x0, po[i]);
      po[i] = __builtin_elementwise_fma((v2f){a4.y, a4.y}, x1, po[i]);
      po[i] = __builtin_elementwise_fma((v2f){a4.z, a4.z}, x2, po[i]);
      po[i] = __builtin_elementwise_fma((v2f){a4.w, a4.w}, x3, po[i]);
    }
  }
  // cross-wave reduction in two rounds of 8 rows (red = 32KB)
#pragma unroll
  for (int h = 0; h < 2; ++h) {
#pragma unroll
    for (int i = 0; i < 8; ++i) red[wid][i][lane] = po[h * 8 + i];
    __syncthreads();
    {
      const int i2 = wid, dl = lane;
      v2f s = red[0][i2][dl];
#pragma unroll
      for (int p = 1; p < 8; ++p) s += red[p][i2][dl];
      *(v2f*)&out[(size_t)(b * NL + i0 + h * 8 + i2) * ND + dl * 2] = s;
    }
    if (h == 0) __syncthreads();
  }
}

extern "C" void kernel_launch(void* const* d_in, const int* in_sizes, int n_in,
                              void* d_out, int out_size, void* d_ws,
                              size_t ws_size, hipStream_t stream) {
  const float* inp = (const float*)d_in[0];
  const float* uw = (const float*)d_in[1];
  const float* vw = (const float*)d_in[2];
  const float* aw = (const float*)d_in[3];
  float* out = (float*)d_out;
  float* attn = out + NB * NL * ND;        // tuple order: (out, attn)
  float* eqp = (float*)d_ws;               // [B][32][512][4] packed exp2 q
  float* ekq = eqp + NB * ND * NL;         // [B][32][128][16] tile-interleaved
  size_t need = (size_t)2 * NB * ND * NL * 4 + 32768 * 4;
  float* wp = (ws_size >= need) ? (ekq + NB * ND * NL) : (attn);
  float* uwp = wp;                 // 16384
  float* vwp = wp + 16384;         // 16384
  wpack_kernel<<<dim3(32), 256, 0, stream>>>(uw, vw, uwp, vwp);
  qk_kernel<<<dim3(NB * 64), 256, 0, stream>>>(inp, uwp, vwp, eqp, ekq);
  attn_kernel<<<dim3(NB * 32), 512, 0, stream>>>(inp, aw, eqp, ekq, out, attn);
}